// Round 15
// baseline (1123.397 us; speedup 1.0000x reference)
//
#include <hip/hip_runtime.h>
#include <cstdint>
#include <cstddef>

#define DI __device__ __forceinline__

typedef __bf16 bf16x8 __attribute__((ext_vector_type(8)));
typedef float  f32x4  __attribute__((ext_vector_type(4)));

constexpr int kE = 1024;
constexpr int kM = 8192;
constexpr float kSlope = 0.01f;

DI float bf2f(ushort u) { union { uint32_t i; float f; } v; v.i = ((uint32_t)u) << 16; return v.f; }
DI ushort f2bf(float f) {
    union { float f; uint32_t i; } v; v.f = f;
    return (ushort)((v.i + 0x7FFFu + ((v.i >> 16) & 1u)) >> 16);
}
DI bf16x8 ld8f(const float* p) {
    const float4 f0 = *(const float4*)p;
    const float4 f1 = *(const float4*)(p + 4);
    union { bf16x8 v; ushort u[8]; } o;
    o.u[0] = f2bf(f0.x); o.u[1] = f2bf(f0.y); o.u[2] = f2bf(f0.z); o.u[3] = f2bf(f0.w);
    o.u[4] = f2bf(f1.x); o.u[5] = f2bf(f1.y); o.u[6] = f2bf(f1.z); o.u[7] = f2bf(f1.w);
    return o.v;
}
template<typename T> DI float ldf(const T* p);
template<> DI float ldf<ushort>(const ushort* p) { return bf2f(*p); }
template<> DI float ldf<float>(const float* p) { return *p; }

DI void gload16(const void* g, void* lds) {
    __builtin_amdgcn_global_load_lds((const __attribute__((address_space(1))) void*)g,
                                     (__attribute__((address_space(3))) void*)lds, 16, 0, 0);
}

// XOR swizzle helper (16B-slot granularity on bits 4..6)
DI int swz7(int r) { return ((r ^ (r >> 3)) & 7) << 4; }

// ---------------------------------------------------------------------------
// cvt_pack: fp32 weights -> packed bf16 WB; x,y -> bf16; biases -> packed fp32
// ---------------------------------------------------------------------------
struct PtrTab { const float* w[16]; const float* b[16]; const float* x; const float* y; };

__global__ __launch_bounds__(256)
void cvt_pack(PtrTab t, ushort* __restrict__ WB, ushort* __restrict__ Xb,
              ushort* __restrict__ Yb, float* __restrict__ BP)
{
    const int blk = blockIdx.x, tid = threadIdx.x;
    if (blk < 16384) {
        const float* src; ushort* dst; size_t idx;
        if (blk < 8192)       { const int w = blk >> 9; idx = (size_t)(blk & 511) * 2048 + tid * 8; src = t.w[w]; dst = WB + (size_t)w * 1048576; }
        else if (blk < 12288) { idx = (size_t)(blk - 8192) * 2048 + tid * 8;  src = t.x; dst = Xb; }
        else                  { idx = (size_t)(blk - 12288) * 2048 + tid * 8; src = t.y; dst = Yb; }
        *(bf16x8*)(dst + idx) = ld8f(src + idx);
    } else {
        const size_t i = (size_t)(blk - 16384) * 2048 + tid * 8;
        const int w = (int)(i >> 10), off = (int)(i & 1023);
        *(float4*)(BP + i)     = *(const float4*)(t.b[w] + off);
        *(float4*)(BP + i + 4) = *(const float4*)(t.b[w] + off + 4);
    }
}

// ---------------------------------------------------------------------------
// 128x128-tile bf16 GEMM: out[8192,1024] = epi((A @ W^T + bias) * oscale)
// BK=32, 4 waves(2x2), global_load_lds staging, double-buffered, slab/XCD
// swizzle. oscale pre-folds the attention 1/sqrt(d) into the q projection.
// VT mode: swapped-operand MFMA computes C^T; transposed store into
// vt_out[(b*1024 + d)*1024 + t].
// ---------------------------------------------------------------------------
template<int ACT, int RESID, int VT, typename TR, typename TO>
__global__ __launch_bounds__(256)
void gemm_bf16(const ushort* __restrict__ A, const ushort* __restrict__ W,
               const float* __restrict__ bias, const TR* __restrict__ resb,
               TO* __restrict__ out, int N, ushort* __restrict__ vt_out, int vtcol0,
               float oscale)
{
    __shared__ __align__(16) char sm[2][16384];   // [buf][A 8K | W 8K]
    constexpr int K = 1024;
    const int tid = threadIdx.x, l = tid & 63, wid = tid >> 6;
    const int wm = wid >> 1, wn = wid & 1;

    const int cpx = gridDim.x >> 3;
    const int sb = (blockIdx.x & 7) * cpx + (blockIdx.x >> 3);
    // slab decomposition: 512 blocks per slab = 64 row-tiles x 8 col-tiles
    const int slab = sb >> 9, rr = sb & 511;
    const int bm = rr >> 3, bn = (slab << 3) + (rr & 7);
    const size_t row0 = (size_t)bm << 7, col0 = (size_t)bn << 7;
    const bool isvt = VT && ((int)col0 >= vtcol0);

    // staging source precompute: o = (wid*2+i)*1024 + l*16
    const int o0 = (wid * 2) * 1024 + (l << 4), o1 = o0 + 1024;
    const int r0s = o0 >> 6, c0s = ((o0 >> 4) & 3) ^ ((r0s >> 1) & 3);
    const int r1s = o1 >> 6, c1s = ((o1 >> 4) & 3) ^ ((r1s >> 1) & 3);
    const ushort* gA0 = A + (row0 + r0s) * K + c0s * 8;
    const ushort* gA1 = A + (row0 + r1s) * K + c1s * 8;
    const ushort* gW0 = W + (col0 + r0s) * K + c0s * 8;
    const ushort* gW1 = W + (col0 + r1s) * K + c1s * 8;
    const int d0 = (wid * 2) * 1024, d1 = d0 + 1024;

    f32x4 acc[4][4] = {};

    { // prologue: stage tile 0
        gload16(gA0, sm[0] + d0); gload16(gA1, sm[0] + d1);
        gload16(gW0, sm[0] + 8192 + d0); gload16(gW1, sm[0] + 8192 + d1);
    }
    __syncthreads();

    for (int kt = 0; kt < 32; ++kt) {
        const int cur = kt & 1;
        if (kt + 1 < 32) {
            const int ko = (kt + 1) << 5;
            char* nb = sm[cur ^ 1];
            gload16(gA0 + ko, nb + d0); gload16(gA1 + ko, nb + d1);
            gload16(gW0 + ko, nb + 8192 + d0); gload16(gW1 + ko, nb + 8192 + d1);
        }
        const char* At = sm[cur];
        const char* Wt = sm[cur] + 8192;
        bf16x8 af[4], bfr[4];
        #pragma unroll
        for (int mi = 0; mi < 4; ++mi) {
            const int r = (wm << 6) + (mi << 4) + (l & 15);
            af[mi] = *(const bf16x8*)(At + r * 64 + ((((l >> 4) ^ ((r >> 1) & 3))) << 4));
        }
        #pragma unroll
        for (int ni = 0; ni < 4; ++ni) {
            const int r = (wn << 6) + (ni << 4) + (l & 15);
            bfr[ni] = *(const bf16x8*)(Wt + r * 64 + ((((l >> 4) ^ ((r >> 1) & 3))) << 4));
        }
        if (!isvt) {
            #pragma unroll
            for (int mi = 0; mi < 4; ++mi)
                #pragma unroll
                for (int ni = 0; ni < 4; ++ni)
                    acc[mi][ni] = __builtin_amdgcn_mfma_f32_16x16x32_bf16(af[mi], bfr[ni], acc[mi][ni], 0, 0, 0);
        } else {
            // swapped operands: D' = W_tile · A_tile^T = C^T
            #pragma unroll
            for (int mi = 0; mi < 4; ++mi)
                #pragma unroll
                for (int ni = 0; ni < 4; ++ni)
                    acc[mi][ni] = __builtin_amdgcn_mfma_f32_16x16x32_bf16(bfr[ni], af[mi], acc[mi][ni], 0, 0, 0);
        }
        __syncthreads();
    }

    const int cr = (l >> 4) << 2, cc = l & 15;
    if (!isvt) {
        // epilogue: C/D layout col=lane&15, row=(lane>>4)*4+reg (m89-verified)
        #pragma unroll
        for (int mi = 0; mi < 4; ++mi) {
            #pragma unroll
            for (int ni = 0; ni < 4; ++ni) {
                const size_t gr = row0 + (wm << 6) + (mi << 4) + cr;
                const size_t gc = col0 + (wn << 6) + (ni << 4) + cc;
                const float bv = bias[gc];
                #pragma unroll
                for (int r = 0; r < 4; ++r) {
                    float v = (acc[mi][ni][r] + bv) * oscale;
                    if (ACT) v = v > 0.f ? v : v * kSlope;
                    const size_t off = (gr + r) * (size_t)N + gc;
                    if (RESID) v += ldf(resb + off);
                    if constexpr (sizeof(TO) == 4) out[off] = v;
                    else                           out[off] = f2bf(v);
                }
            }
        }
    } else if (VT) {
        // D'[row=d][col=t]: d = col0-vtcol0 + (wn<<6)+(ni<<4)+cr+r, t = row0 + (wm<<6)+(mi<<4)+cc
        #pragma unroll
        for (int mi = 0; mi < 4; ++mi) {
            const size_t t_glob = row0 + (wm << 6) + (mi << 4) + cc;
            const size_t bb = t_glob >> 10;
            const int tt = (int)(t_glob & 1023);
            #pragma unroll
            for (int ni = 0; ni < 4; ++ni) {
                const int gcb = (int)col0 + (wn << 6) + (ni << 4) + cr;
                const int dbase = gcb - vtcol0;
                #pragma unroll
                for (int r = 0; r < 4; ++r) {
                    const float v = acc[mi][ni][r] + bias[gcb + r];
                    vt_out[(((bb << 10) + dbase + r) << 10) + tt] = f2bf(v);
                }
            }
        }
    }
}

// ---------------------------------------------------------------------------
// Flash attention (round-12 structure + T14 register prefetch, round 15).
// One block = (b, h, 64 q-rows); 4 waves x 16 q-rows. Scale pre-folded into
// the q projection. Q/K/QV bf16 row stride ld; V PRE-TRANSPOSED:
// VT[(b*8+h)*128+d][1024 t].
// T14: next tile's 8 uint4 (K rows + V^T rows) are loaded into registers
// BEFORE the current tile's compute phase, so HBM/L2 latency hides under
// QK^T+softmax+PV; after the next barrier they are ds_written immediately.
// (Round-12 loaded between the two barriers — latency fully exposed.)
//  - row-sum via ones-MFMA (lacc) = softmax denominator
//  - defer-rescale (wave-uniform __any)
//  - native __bf16 casts for P
// ---------------------------------------------------------------------------
template<int ADD_QV>
__global__ __launch_bounds__(256)
void attn_fwd(const ushort* __restrict__ Q, const ushort* __restrict__ K,
              const ushort* __restrict__ VT, const ushort* __restrict__ QV,
              ushort* __restrict__ O, int ld)
{
    __shared__ __align__(16) char Kt[64 * 256];    // 16 KiB
    __shared__ __align__(16) char Vt[128 * 128];   // 16 KiB: [d][64 t] bf16
    __shared__ __align__(16) char Pl[4][2048];     // per-wave 16x64 bf16

    const int tid = threadIdx.x;
    const int l = tid & 63, w = tid >> 6;

    const int cpx = gridDim.x >> 3;                 // 1024 blocks -> 128
    const int sb = (blockIdx.x & 7) * cpx + (blockIdx.x >> 3);
    const int qt = sb & 15;
    const int bh = sb >> 4;
    const int h = bh & 7, b = bh >> 3;

    const size_t bi = ((size_t)b << 10) * (size_t)ld + ((size_t)h << 7);
    const size_t bo = ((size_t)b << 10) * 1024 + ((size_t)h << 7);
    const size_t vtoff = ((size_t)bh) << 17;        // (b*8+h)*128*1024
    const size_t qrow0 = (size_t)(qt << 6) + (w << 4);

    // Q fragments (A-side: lane&15 = q-row, (lane>>4)*8 = k-offset)
    bf16x8 qf[4];
    #pragma unroll
    for (int kk = 0; kk < 4; ++kk)
        qf[kk] = *(const bf16x8*)(Q + bi + (qrow0 + (l & 15)) * ld + (kk << 5) + ((l >> 4) << 3));

    f32x4 oacc[8] = {};
    f32x4 lacc = {};                                // row-sum accumulator
    float mrow[4] = {-1e30f, -1e30f, -1e30f, -1e30f};

    bf16x8 vones;
    #pragma unroll
    for (int j = 0; j < 8; ++j) vones[j] = (__bf16)1.0f;

    const int sr = tid >> 4, sc = tid & 15;   // K staging: row group / 16B chunk

    // staging dest/src precompute (kt0-independent)
    int kds[4], vofs[4];
    #pragma unroll
    for (int it = 0; it < 4; ++it) {
        const int r = sr + (it << 4);
        kds[it] = r * 256 + ((sc << 4) ^ swz7(r));
        const int d = it * 32 + (tid >> 3);
        const int s = tid & 7;
        const int c = s ^ ((d ^ (d >> 3)) & 7);
        vofs[it] = d * 1024 + c * 8;
    }
    const int vdst = tid * 16;

    // T14 prefetch registers + loader
    uint4 kreg[4], vreg[4];
    auto loadTile = [&](int kt0) {
        #pragma unroll
        for (int it = 0; it < 4; ++it)
            kreg[it] = *(const uint4*)(K + bi + (size_t)(kt0 * 64 + sr + (it << 4)) * ld + (sc << 3));
        #pragma unroll
        for (int it = 0; it < 4; ++it)
            vreg[it] = *(const uint4*)(VT + vtoff + (size_t)(kt0 << 6) + vofs[it]);
    };
    loadTile(0);

    for (int kt0 = 0; kt0 < 16; ++kt0) {
        __syncthreads();                      // previous tile's LDS reads done
        #pragma unroll
        for (int it = 0; it < 4; ++it) *(uint4*)(Kt + kds[it]) = kreg[it];
        #pragma unroll
        for (int it = 0; it < 4; ++it) *(uint4*)(Vt + it * 4096 + vdst) = vreg[it];
        __syncthreads();                      // staged data visible
        if (kt0 + 1 < 16) loadTile(kt0 + 1);  // issue next-tile loads; latency
                                              // hides under compute below

        // S = Q K^T  (lane holds S[q=(l>>4)*4+r][t=(l&15)+16*ni])
        f32x4 sacc[4] = {};
        #pragma unroll
        for (int ni = 0; ni < 4; ++ni) {
            const int r = (l & 15) + (ni << 4);
            #pragma unroll
            for (int kk = 0; kk < 4; ++kk) {
                bf16x8 kf = *(const bf16x8*)(Kt + r * 256 + ((((kk << 2) + (l >> 4)) << 4) ^ swz7(r)));
                sacc[ni] = __builtin_amdgcn_mfma_f32_16x16x32_bf16(qf[kk], kf, sacc[ni], 0, 0, 0);
            }
        }

        // row max over the 16-lane t-groups
        float m0[4];
        #pragma unroll
        for (int r = 0; r < 4; ++r) {
            float m = fmaxf(fmaxf(sacc[0][r], sacc[1][r]), fmaxf(sacc[2][r], sacc[3][r]));
            #pragma unroll
            for (int msk = 1; msk < 16; msk <<= 1) m = fmaxf(m, __shfl_xor(m, msk, 64));
            m0[r] = m;
        }
        // defer-rescale: only when some row's max grew (wave-uniform branch)
        const bool grow = (m0[0] > mrow[0]) || (m0[1] > mrow[1]) ||
                          (m0[2] > mrow[2]) || (m0[3] > mrow[3]);
        if (__any(grow)) {
            float corr[4];
            #pragma unroll
            for (int r = 0; r < 4; ++r) {
                const float mn = fmaxf(mrow[r], m0[r]);
                corr[r] = __expf(mrow[r] - mn);
                mrow[r] = mn;
            }
            #pragma unroll
            for (int nd = 0; nd < 8; ++nd)
                #pragma unroll
                for (int r = 0; r < 4; ++r) oacc[nd][r] *= corr[r];
            #pragma unroll
            for (int r = 0; r < 4; ++r) lacc[r] *= corr[r];
        }

        // P = exp(S - m) -> bf16 -> per-wave LDS (A-fragment layout)
        char* pw = Pl[w];
        #pragma unroll
        for (int r = 0; r < 4; ++r) {
            const int q = ((l >> 4) << 2) + r;
            const int qo = q * 128, qm = swz7(q);
            const float mr = mrow[r];
            #pragma unroll
            for (int ni = 0; ni < 4; ++ni) {
                const float p = __expf(sacc[ni][r] - mr);
                const int t = (l & 15) + (ni << 4);
                *(__bf16*)(pw + qo + ((t * 2) ^ qm)) = (__bf16)p;
            }
        }

        // PV (+ ones-column row-sum)
        #pragma unroll
        for (int tg = 0; tg < 2; ++tg) {
            const int q = l & 15;
            bf16x8 pf = *(const bf16x8*)(pw + q * 128 + ((((tg << 2) + (l >> 4)) << 4) ^ swz7(q)));
            #pragma unroll
            for (int nd = 0; nd < 8; ++nd) {
                const int d = (nd << 4) + (l & 15);
                const int m = (d ^ (d >> 3)) & 7;
                bf16x8 vf = *(const bf16x8*)(Vt + d * 128 + ((((tg << 2) + (l >> 4)) ^ m) << 4));
                oacc[nd] = __builtin_amdgcn_mfma_f32_16x16x32_bf16(pf, vf, oacc[nd], 0, 0, 0);
            }
            lacc = __builtin_amdgcn_mfma_f32_16x16x32_bf16(pf, vones, lacc, 0, 0, 0);
        }
    }

    // epilogue: O /= l  (+ qv), bf16 store
    const size_t orow = qrow0 + ((l >> 4) << 2);
    #pragma unroll
    for (int r = 0; r < 4; ++r) {
        const float inv = 1.f / lacc[r];
        #pragma unroll
        for (int nd = 0; nd < 8; ++nd) {
            const size_t c = (l & 15) + (nd << 4);
            float v = oacc[nd][r] * inv;
            if (ADD_QV) v += bf2f(QV[bi + (orow + r) * ld + c]);
            O[bo + (orow + r) * 1024 + c] = f2bf(v);
        }
    }
}

// ---------------------------------------------------------------------------
// LayerNorm over (S,E) per batch on bf16 h1.
// ---------------------------------------------------------------------------
__global__ void ln_partial(const ushort* __restrict__ h1, float2* __restrict__ part)
{
    __shared__ float sa[8];
    const size_t off = ((size_t)blockIdx.x) << 15;
    float s = 0.f, s2 = 0.f;
    for (int i = threadIdx.x; i < 4096; i += 256) {
        uint4 u = *(const uint4*)(h1 + off + (size_t)i * 8);
        const ushort* e = (const ushort*)&u;
        #pragma unroll
        for (int j = 0; j < 8; ++j) { const float v = bf2f(e[j]); s += v; s2 += v * v; }
    }
    #pragma unroll
    for (int m = 1; m < 64; m <<= 1) { s += __shfl_xor(s, m, 64); s2 += __shfl_xor(s2, m, 64); }
    const int w = threadIdx.x >> 6;
    if ((threadIdx.x & 63) == 0) { sa[w * 2] = s; sa[w * 2 + 1] = s2; }
    __syncthreads();
    if (threadIdx.x == 0)
        part[blockIdx.x] = make_float2(sa[0] + sa[2] + sa[4] + sa[6], sa[1] + sa[3] + sa[5] + sa[7]);
}

__global__ void ln_finish(const float2* __restrict__ part, float2* __restrict__ stats)
{
    const int b = threadIdx.x;
    if (b < 8) {
        float s = 0.f, s2 = 0.f;
        for (int c = 0; c < 32; ++c) { const float2 v = part[b * 32 + c]; s += v.x; s2 += v.y; }
        const float mu = s * (1.f / 1048576.f);
        const float var = s2 * (1.f / 1048576.f) - mu * mu;
        stats[b] = make_float2(mu, rsqrtf(var + 1e-5f));
    }
}

__global__ void ln_apply(const ushort* __restrict__ h1, const float2* __restrict__ stats,
                         const float* __restrict__ gw, const float* __restrict__ gb,
                         ushort* __restrict__ hn)
{
    const size_t i = ((size_t)blockIdx.x * 256 + threadIdx.x) * 8;
    const int b = (int)(i >> 20);
    const size_t r = i & 1048575;
    const float2 st = stats[b];
    uint4 uv = *(const uint4*)(h1 + i);
    const float4 w0 = *(const float4*)(gw + r);
    const float4 w1 = *(const float4*)(gw + r + 4);
    const float4 b0 = *(const float4*)(gb + r);
    const float4 b1 = *(const float4*)(gb + r + 4);
    const float wv[8] = {w0.x, w0.y, w0.z, w0.w, w1.x, w1.y, w1.z, w1.w};
    const float bv[8] = {b0.x, b0.y, b0.z, b0.w, b1.x, b1.y, b1.z, b1.w};
    const ushort* ev = (const ushort*)&uv;
    ushort o[8];
    #pragma unroll
    for (int j = 0; j < 8; ++j)
        o[j] = f2bf((bf2f(ev[j]) - st.x) * st.y * wv[j] + bv[j]);
    *(uint4*)(hn + i) = *(const uint4*)o;
}

// ---------------------------------------------------------------------------
extern "C" void kernel_launch(void* const* d_in, const int* in_sizes, int n_in,
                              void* d_out, int out_size, void* d_ws, size_t ws_size,
                              hipStream_t stream)
{
    (void)in_sizes; (void)n_in; (void)out_size; (void)ws_size;
    auto P = [&](int i) { return (const float*)d_in[i]; };

    const size_t MB = 1u << 20;
    char* ws = (char*)d_ws;
    ushort* WB = (ushort*)ws;                       // 32 MB packed bf16 weights
    ushort* B0 = (ushort*)(ws + 32 * MB);           // 6 x 16 MB bf16 buffers
    ushort* B1 = (ushort*)(ws + 48 * MB);
    ushort* B2 = (ushort*)(ws + 64 * MB);
    ushort* B3 = (ushort*)(ws + 80 * MB);
    ushort* B4 = (ushort*)(ws + 96 * MB);
    ushort* B5 = (ushort*)(ws + 112 * MB);
    float*  BP = (float*)(ws + 128 * MB);           // 64 KB packed fp32 biases
    float2* PART = (float2*)(ws + 128 * MB + 65536);
    float2* STATS = PART + 256;

    PtrTab tab;
    const int wsrc[16] = {2,4,6,8,10,14,16,18,20,22,24,26,28,30,32,34};
    for (int i = 0; i < 16; ++i) { tab.w[i] = P(wsrc[i]); tab.b[i] = P(wsrc[i] + 1); }
    tab.x = P(0); tab.y = P(1);

    const dim3 blk(256), gg(512);
    const float SA_SCALE = 0.08838834764831845f;    // 1/sqrt(128), folded into q proj
    auto Wp = [&](int w) { return WB + (size_t)w * 1048576; };
    auto Bp = [&](int w) { return BP + (size_t)w * 1024; };
    const ushort* NUS = nullptr;

    // x_bf16 -> B4, y_bf16 -> B5
    cvt_pack<<<dim3(16392), blk, 0, stream>>>(tab, WB, B4, B5, BP);

    // --- cross attention (all GEMMs N=1024) ---
    gemm_bf16<0,0,0,ushort,ushort><<<gg, blk, 0, stream>>>(B4, Wp(0), Bp(0), NUS, B0, 1024, nullptr, 0, 1.0f);  // q  -> B0
    gemm_bf16<0,0,0,ushort,ushort><<<gg, blk, 0, stream>>>(B4, Wp(1), Bp(1), NUS, B1, 1024, nullptr, 0, 1.0f);  // qv -> B1
    gemm_bf16<0,0,0,ushort,ushort><<<gg, blk, 0, stream>>>(B5, Wp(2), Bp(2), NUS, B2, 1024, nullptr, 0, 1.0f);  // k  -> B2
    gemm_bf16<0,0,1,ushort,ushort><<<gg, blk, 0, stream>>>(B5, Wp(3), Bp(3), NUS, B3, 1024, B3, 0, 1.0f);       // kv^T -> B3
    attn_fwd<1><<<dim3(1024), blk, 0, stream>>>(B0, B2, B3, B1, B4, 1024);                                       // -> B4
    gemm_bf16<0,1,0,float,ushort><<<gg, blk, 0, stream>>>(B4, Wp(4), Bp(4), P(0), B5, 1024, nullptr, 0, 1.0f);   // h1 = x + o(ca) -> B5

    // --- LayerNorm over (S,E) per batch: h1=B5 -> hn=B0 ---
    ln_partial<<<dim3(256), blk, 0, stream>>>(B5, PART);
    ln_finish<<<dim3(1), dim3(64), 0, stream>>>(PART, STATS);
    ln_apply<<<dim3(4096), blk, 0, stream>>>(B5, STATS, P(12), P(13), B0);

    // --- FeedForward: hn=B0 -> h2=B3 ---
    gemm_bf16<1,0,0,ushort,ushort><<<gg, blk, 0, stream>>>(B0, Wp(5), Bp(5), NUS, B1, 1024, nullptr, 0, 1.0f);   // f1
    gemm_bf16<1,0,0,ushort,ushort><<<gg, blk, 0, stream>>>(B1, Wp(6), Bp(6), NUS, B2, 1024, nullptr, 0, 1.0f);   // f2
    gemm_bf16<1,1,0,ushort,ushort><<<gg, blk, 0, stream>>>(B2, Wp(7), Bp(7), B0, B3, 1024, nullptr, 0, 1.0f);    // h2 = hn + lr(f3)

    // --- self attention 1 (input h2=B3) ---
    gemm_bf16<0,0,0,ushort,ushort><<<gg, blk, 0, stream>>>(B3, Wp(8),  Bp(8),  NUS, B0, 1024, nullptr, 0, SA_SCALE); // q1*scale -> B0
    gemm_bf16<0,0,0,ushort,ushort><<<gg, blk, 0, stream>>>(B3, Wp(9),  Bp(9),  NUS, B1, 1024, nullptr, 0, 1.0f);     // k1 -> B1
    gemm_bf16<0,0,1,ushort,ushort><<<gg, blk, 0, stream>>>(B3, Wp(10), Bp(10), NUS, B2, 1024, B2, 0, 1.0f);          // v1^T -> B2
    attn_fwd<0><<<dim3(1024), blk, 0, stream>>>(B0, B1, B2, nullptr, B4, 1024);                                      // -> B4
    gemm_bf16<0,0,0,ushort,ushort><<<gg, blk, 0, stream>>>(B4, Wp(11), Bp(11), NUS, B5, 1024, nullptr, 0, 1.0f);     // h3 -> B5

    // --- self attention 2 (input h3=B5) ---
    gemm_bf16<0,0,0,ushort,ushort><<<gg, blk, 0, stream>>>(B5, Wp(12), Bp(12), NUS, B0, 1024, nullptr, 0, SA_SCALE); // q2*scale -> B0
    gemm_bf16<0,0,0,ushort,ushort><<<gg, blk, 0, stream>>>(B5, Wp(13), Bp(13), NUS, B1, 1024, nullptr, 0, 1.0f);     // k2 -> B1
    gemm_bf16<0,0,1,ushort,ushort><<<gg, blk, 0, stream>>>(B5, Wp(14), Bp(14), NUS, B2, 1024, B2, 0, 1.0f);          // v2^T -> B2
    attn_fwd<0><<<dim3(1024), blk, 0, stream>>>(B0, B1, B2, nullptr, B4, 1024);                                      // -> B4
    gemm_bf16<0,0,0,ushort,float><<<gg, blk, 0, stream>>>(B4, Wp(15), Bp(15), NUS, (float*)d_out, 1024, nullptr, 0, 1.0f);
}

// Round 16
// 765.462 us; speedup vs baseline: 1.4676x; 1.4676x over previous
//
#include <hip/hip_runtime.h>
#include <cstdint>
#include <cstddef>

#define DI __device__ __forceinline__

typedef __bf16 bf16x8 __attribute__((ext_vector_type(8)));
typedef float  f32x4  __attribute__((ext_vector_type(4)));

constexpr int kE = 1024;
constexpr int kM = 8192;
constexpr float kSlope = 0.01f;

DI float bf2f(ushort u) { union { uint32_t i; float f; } v; v.i = ((uint32_t)u) << 16; return v.f; }
DI ushort f2bf(float f) {
    union { float f; uint32_t i; } v; v.f = f;
    return (ushort)((v.i + 0x7FFFu + ((v.i >> 16) & 1u)) >> 16);
}
DI bf16x8 ld8f(const float* p) {
    const float4 f0 = *(const float4*)p;
    const float4 f1 = *(const float4*)(p + 4);
    union { bf16x8 v; ushort u[8]; } o;
    o.u[0] = f2bf(f0.x); o.u[1] = f2bf(f0.y); o.u[2] = f2bf(f0.z); o.u[3] = f2bf(f0.w);
    o.u[4] = f2bf(f1.x); o.u[5] = f2bf(f1.y); o.u[6] = f2bf(f1.z); o.u[7] = f2bf(f1.w);
    return o.v;
}
template<typename T> DI float ldf(const T* p);
template<> DI float ldf<ushort>(const ushort* p) { return bf2f(*p); }
template<> DI float ldf<float>(const float* p) { return *p; }

DI void gload16(const void* g, void* lds) {
    __builtin_amdgcn_global_load_lds((const __attribute__((address_space(1))) void*)g,
                                     (__attribute__((address_space(3))) void*)lds, 16, 0, 0);
}

// XOR swizzle helper (16B-slot granularity on bits 4..6)
DI int swz7(int r) { return ((r ^ (r >> 3)) & 7) << 4; }

// ---------------------------------------------------------------------------
// cvt_pack: fp32 weights -> packed bf16 WB; x,y -> bf16; biases -> packed fp32
// ---------------------------------------------------------------------------
struct PtrTab { const float* w[16]; const float* b[16]; const float* x; const float* y; };

__global__ __launch_bounds__(256)
void cvt_pack(PtrTab t, ushort* __restrict__ WB, ushort* __restrict__ Xb,
              ushort* __restrict__ Yb, float* __restrict__ BP)
{
    const int blk = blockIdx.x, tid = threadIdx.x;
    if (blk < 16384) {
        const float* src; ushort* dst; size_t idx;
        if (blk < 8192)       { const int w = blk >> 9; idx = (size_t)(blk & 511) * 2048 + tid * 8; src = t.w[w]; dst = WB + (size_t)w * 1048576; }
        else if (blk < 12288) { idx = (size_t)(blk - 8192) * 2048 + tid * 8;  src = t.x; dst = Xb; }
        else                  { idx = (size_t)(blk - 12288) * 2048 + tid * 8; src = t.y; dst = Yb; }
        *(bf16x8*)(dst + idx) = ld8f(src + idx);
    } else {
        const size_t i = (size_t)(blk - 16384) * 2048 + tid * 8;
        const int w = (int)(i >> 10), off = (int)(i & 1023);
        *(float4*)(BP + i)     = *(const float4*)(t.b[w] + off);
        *(float4*)(BP + i + 4) = *(const float4*)(t.b[w] + off + 4);
    }
}

// ---------------------------------------------------------------------------
// 128x128-tile bf16 GEMM: out[8192,1024] = epi((A @ W^T + bias) * oscale)
// BK=32, 4 waves(2x2), global_load_lds staging, double-buffered, slab/XCD
// swizzle. oscale pre-folds the attention 1/sqrt(d) into the q projection.
// VT mode: swapped-operand MFMA computes C^T; transposed store into
// vt_out[(b*1024 + d)*1024 + t].
// ---------------------------------------------------------------------------
template<int ACT, int RESID, int VT, typename TR, typename TO>
__global__ __launch_bounds__(256)
void gemm_bf16(const ushort* __restrict__ A, const ushort* __restrict__ W,
               const float* __restrict__ bias, const TR* __restrict__ resb,
               TO* __restrict__ out, int N, ushort* __restrict__ vt_out, int vtcol0,
               float oscale)
{
    __shared__ __align__(16) char sm[2][16384];   // [buf][A 8K | W 8K]
    constexpr int K = 1024;
    const int tid = threadIdx.x, l = tid & 63, wid = tid >> 6;
    const int wm = wid >> 1, wn = wid & 1;

    const int cpx = gridDim.x >> 3;
    const int sb = (blockIdx.x & 7) * cpx + (blockIdx.x >> 3);
    // slab decomposition: 512 blocks per slab = 64 row-tiles x 8 col-tiles
    const int slab = sb >> 9, rr = sb & 511;
    const int bm = rr >> 3, bn = (slab << 3) + (rr & 7);
    const size_t row0 = (size_t)bm << 7, col0 = (size_t)bn << 7;
    const bool isvt = VT && ((int)col0 >= vtcol0);

    // staging source precompute: o = (wid*2+i)*1024 + l*16
    const int o0 = (wid * 2) * 1024 + (l << 4), o1 = o0 + 1024;
    const int r0s = o0 >> 6, c0s = ((o0 >> 4) & 3) ^ ((r0s >> 1) & 3);
    const int r1s = o1 >> 6, c1s = ((o1 >> 4) & 3) ^ ((r1s >> 1) & 3);
    const ushort* gA0 = A + (row0 + r0s) * K + c0s * 8;
    const ushort* gA1 = A + (row0 + r1s) * K + c1s * 8;
    const ushort* gW0 = W + (col0 + r0s) * K + c0s * 8;
    const ushort* gW1 = W + (col0 + r1s) * K + c1s * 8;
    const int d0 = (wid * 2) * 1024, d1 = d0 + 1024;

    f32x4 acc[4][4] = {};

    { // prologue: stage tile 0
        gload16(gA0, sm[0] + d0); gload16(gA1, sm[0] + d1);
        gload16(gW0, sm[0] + 8192 + d0); gload16(gW1, sm[0] + 8192 + d1);
    }
    __syncthreads();

    for (int kt = 0; kt < 32; ++kt) {
        const int cur = kt & 1;
        if (kt + 1 < 32) {
            const int ko = (kt + 1) << 5;
            char* nb = sm[cur ^ 1];
            gload16(gA0 + ko, nb + d0); gload16(gA1 + ko, nb + d1);
            gload16(gW0 + ko, nb + 8192 + d0); gload16(gW1 + ko, nb + 8192 + d1);
        }
        const char* At = sm[cur];
        const char* Wt = sm[cur] + 8192;
        bf16x8 af[4], bfr[4];
        #pragma unroll
        for (int mi = 0; mi < 4; ++mi) {
            const int r = (wm << 6) + (mi << 4) + (l & 15);
            af[mi] = *(const bf16x8*)(At + r * 64 + ((((l >> 4) ^ ((r >> 1) & 3))) << 4));
        }
        #pragma unroll
        for (int ni = 0; ni < 4; ++ni) {
            const int r = (wn << 6) + (ni << 4) + (l & 15);
            bfr[ni] = *(const bf16x8*)(Wt + r * 64 + ((((l >> 4) ^ ((r >> 1) & 3))) << 4));
        }
        if (!isvt) {
            #pragma unroll
            for (int mi = 0; mi < 4; ++mi)
                #pragma unroll
                for (int ni = 0; ni < 4; ++ni)
                    acc[mi][ni] = __builtin_amdgcn_mfma_f32_16x16x32_bf16(af[mi], bfr[ni], acc[mi][ni], 0, 0, 0);
        } else {
            // swapped operands: D' = W_tile · A_tile^T = C^T
            #pragma unroll
            for (int mi = 0; mi < 4; ++mi)
                #pragma unroll
                for (int ni = 0; ni < 4; ++ni)
                    acc[mi][ni] = __builtin_amdgcn_mfma_f32_16x16x32_bf16(bfr[ni], af[mi], acc[mi][ni], 0, 0, 0);
        }
        __syncthreads();
    }

    const int cr = (l >> 4) << 2, cc = l & 15;
    if (!isvt) {
        // epilogue: C/D layout col=lane&15, row=(lane>>4)*4+reg (m89-verified)
        #pragma unroll
        for (int mi = 0; mi < 4; ++mi) {
            #pragma unroll
            for (int ni = 0; ni < 4; ++ni) {
                const size_t gr = row0 + (wm << 6) + (mi << 4) + cr;
                const size_t gc = col0 + (wn << 6) + (ni << 4) + cc;
                const float bv = bias[gc];
                #pragma unroll
                for (int r = 0; r < 4; ++r) {
                    float v = (acc[mi][ni][r] + bv) * oscale;
                    if (ACT) v = v > 0.f ? v : v * kSlope;
                    const size_t off = (gr + r) * (size_t)N + gc;
                    if (RESID) v += ldf(resb + off);
                    if constexpr (sizeof(TO) == 4) out[off] = v;
                    else                           out[off] = f2bf(v);
                }
            }
        }
    } else if (VT) {
        // D'[row=d][col=t]: d = col0-vtcol0 + (wn<<6)+(ni<<4)+cr+r, t = row0 + (wm<<6)+(mi<<4)+cc
        #pragma unroll
        for (int mi = 0; mi < 4; ++mi) {
            const size_t t_glob = row0 + (wm << 6) + (mi << 4) + cc;
            const size_t bb = t_glob >> 10;
            const int tt = (int)(t_glob & 1023);
            #pragma unroll
            for (int ni = 0; ni < 4; ++ni) {
                const int gcb = (int)col0 + (wn << 6) + (ni << 4) + cr;
                const int dbase = gcb - vtcol0;
                #pragma unroll
                for (int r = 0; r < 4; ++r) {
                    const float v = acc[mi][ni][r] + bias[gcb + r];
                    vt_out[(((bb << 10) + dbase + r) << 10) + tt] = f2bf(v);
                }
            }
        }
    }
}

// ---------------------------------------------------------------------------
// Flash attention (round-12 structure + T14 register prefetch, round 16).
// One block = (b, h, 64 q-rows); 4 waves x 16 q-rows. Scale pre-folded into
// the q projection. Q/K/QV bf16 row stride ld; V PRE-TRANSPOSED:
// VT[(b*8+h)*128+d][1024 t].
// T14 prefetch, spill-proof form: round 15's lambda-captured kreg[]/vreg[]
// arrays became ADDRESSABLE -> scratch (WRITE_SIZE 16MB -> 293MB, 2.3x slower;
// rule #20). Now eight NAMED uint4 registers assigned via a macro — nothing
// address-taken, nothing runtime-indexed. Next tile's loads issue before the
// compute phase so HBM/L2 latency hides under QK^T+softmax+PV.
//  - row-sum via ones-MFMA (lacc) = softmax denominator
//  - defer-rescale (wave-uniform __any)
//  - native __bf16 casts for P
// ---------------------------------------------------------------------------
template<int ADD_QV>
__global__ __launch_bounds__(256)
void attn_fwd(const ushort* __restrict__ Q, const ushort* __restrict__ K,
              const ushort* __restrict__ VT, const ushort* __restrict__ QV,
              ushort* __restrict__ O, int ld)
{
    __shared__ __align__(16) char Kt[64 * 256];    // 16 KiB
    __shared__ __align__(16) char Vt[128 * 128];   // 16 KiB: [d][64 t] bf16
    __shared__ __align__(16) char Pl[4][2048];     // per-wave 16x64 bf16

    const int tid = threadIdx.x;
    const int l = tid & 63, w = tid >> 6;

    const int cpx = gridDim.x >> 3;                 // 1024 blocks -> 128
    const int sb = (blockIdx.x & 7) * cpx + (blockIdx.x >> 3);
    const int qt = sb & 15;
    const int bh = sb >> 4;
    const int h = bh & 7, b = bh >> 3;

    const size_t bi = ((size_t)b << 10) * (size_t)ld + ((size_t)h << 7);
    const size_t bo = ((size_t)b << 10) * 1024 + ((size_t)h << 7);
    const size_t vtoff = ((size_t)bh) << 17;        // (b*8+h)*128*1024
    const size_t qrow0 = (size_t)(qt << 6) + (w << 4);

    // Q fragments (A-side: lane&15 = q-row, (lane>>4)*8 = k-offset)
    bf16x8 qf[4];
    #pragma unroll
    for (int kk = 0; kk < 4; ++kk)
        qf[kk] = *(const bf16x8*)(Q + bi + (qrow0 + (l & 15)) * ld + (kk << 5) + ((l >> 4) << 3));

    f32x4 oacc[8] = {};
    f32x4 lacc = {};                                // row-sum accumulator
    float mrow[4] = {-1e30f, -1e30f, -1e30f, -1e30f};

    bf16x8 vones;
    #pragma unroll
    for (int j = 0; j < 8; ++j) vones[j] = (__bf16)1.0f;

    const int sr = tid >> 4, sc = tid & 15;   // K staging: row group / 16B chunk

    // staging dest/src precompute (kt0-independent; const-indexed only)
    const int kds0 = (sr +  0) * 256 + ((sc << 4) ^ swz7(sr +  0));
    const int kds1 = (sr + 16) * 256 + ((sc << 4) ^ swz7(sr + 16));
    const int kds2 = (sr + 32) * 256 + ((sc << 4) ^ swz7(sr + 32));
    const int kds3 = (sr + 48) * 256 + ((sc << 4) ^ swz7(sr + 48));
    const int dV = tid >> 3, sV = tid & 7;
    const int vof0 = (dV +  0) * 1024 + (sV ^ (((dV +  0) ^ ((dV +  0) >> 3)) & 7)) * 8;
    const int vof1 = (dV + 32) * 1024 + (sV ^ (((dV + 32) ^ ((dV + 32) >> 3)) & 7)) * 8;
    const int vof2 = (dV + 64) * 1024 + (sV ^ (((dV + 64) ^ ((dV + 64) >> 3)) & 7)) * 8;
    const int vof3 = (dV + 96) * 1024 + (sV ^ (((dV + 96) ^ ((dV + 96) >> 3)) & 7)) * 8;
    const int vdst = tid * 16;

    // T14 prefetch: named registers, never address-taken
    uint4 k0, k1, k2, k3, v0, v1, v2, v3;
#define LOAD_TILE(KT)                                                                   \
    {                                                                                   \
        const ushort* kb = K + bi + (size_t)((KT) * 64 + sr) * ld + (sc << 3);          \
        k0 = *(const uint4*)kb;                                                         \
        k1 = *(const uint4*)(kb + (size_t)16 * ld);                                     \
        k2 = *(const uint4*)(kb + (size_t)32 * ld);                                     \
        k3 = *(const uint4*)(kb + (size_t)48 * ld);                                     \
        const ushort* vb = VT + vtoff + (size_t)((KT) << 6);                            \
        v0 = *(const uint4*)(vb + vof0);                                                \
        v1 = *(const uint4*)(vb + vof1);                                                \
        v2 = *(const uint4*)(vb + vof2);                                                \
        v3 = *(const uint4*)(vb + vof3);                                                \
    }
    LOAD_TILE(0);

    for (int kt0 = 0; kt0 < 16; ++kt0) {
        __syncthreads();                      // previous tile's LDS reads done
        *(uint4*)(Kt + kds0) = k0;
        *(uint4*)(Kt + kds1) = k1;
        *(uint4*)(Kt + kds2) = k2;
        *(uint4*)(Kt + kds3) = k3;
        *(uint4*)(Vt + vdst)         = v0;
        *(uint4*)(Vt + 4096 + vdst)  = v1;
        *(uint4*)(Vt + 8192 + vdst)  = v2;
        *(uint4*)(Vt + 12288 + vdst) = v3;
        __syncthreads();                      // staged data visible
        if (kt0 + 1 < 16) LOAD_TILE(kt0 + 1); // latency hides under compute

        // S = Q K^T  (lane holds S[q=(l>>4)*4+r][t=(l&15)+16*ni])
        f32x4 sacc[4] = {};
        #pragma unroll
        for (int ni = 0; ni < 4; ++ni) {
            const int r = (l & 15) + (ni << 4);
            #pragma unroll
            for (int kk = 0; kk < 4; ++kk) {
                bf16x8 kf = *(const bf16x8*)(Kt + r * 256 + ((((kk << 2) + (l >> 4)) << 4) ^ swz7(r)));
                sacc[ni] = __builtin_amdgcn_mfma_f32_16x16x32_bf16(qf[kk], kf, sacc[ni], 0, 0, 0);
            }
        }

        // row max over the 16-lane t-groups
        float m0[4];
        #pragma unroll
        for (int r = 0; r < 4; ++r) {
            float m = fmaxf(fmaxf(sacc[0][r], sacc[1][r]), fmaxf(sacc[2][r], sacc[3][r]));
            #pragma unroll
            for (int msk = 1; msk < 16; msk <<= 1) m = fmaxf(m, __shfl_xor(m, msk, 64));
            m0[r] = m;
        }
        // defer-rescale: only when some row's max grew (wave-uniform branch)
        const bool grow = (m0[0] > mrow[0]) || (m0[1] > mrow[1]) ||
                          (m0[2] > mrow[2]) || (m0[3] > mrow[3]);
        if (__any(grow)) {
            float corr[4];
            #pragma unroll
            for (int r = 0; r < 4; ++r) {
                const float mn = fmaxf(mrow[r], m0[r]);
                corr[r] = __expf(mrow[r] - mn);
                mrow[r] = mn;
            }
            #pragma unroll
            for (int nd = 0; nd < 8; ++nd)
                #pragma unroll
                for (int r = 0; r < 4; ++r) oacc[nd][r] *= corr[r];
            #pragma unroll
            for (int r = 0; r < 4; ++r) lacc[r] *= corr[r];
        }

        // P = exp(S - m) -> bf16 -> per-wave LDS (A-fragment layout)
        char* pw = Pl[w];
        #pragma unroll
        for (int r = 0; r < 4; ++r) {
            const int q = ((l >> 4) << 2) + r;
            const int qo = q * 128, qm = swz7(q);
            const float mr = mrow[r];
            #pragma unroll
            for (int ni = 0; ni < 4; ++ni) {
                const float p = __expf(sacc[ni][r] - mr);
                const int t = (l & 15) + (ni << 4);
                *(__bf16*)(pw + qo + ((t * 2) ^ qm)) = (__bf16)p;
            }
        }

        // PV (+ ones-column row-sum)
        #pragma unroll
        for (int tg = 0; tg < 2; ++tg) {
            const int q = l & 15;
            bf16x8 pf = *(const bf16x8*)(pw + q * 128 + ((((tg << 2) + (l >> 4)) << 4) ^ swz7(q)));
            #pragma unroll
            for (int nd = 0; nd < 8; ++nd) {
                const int d = (nd << 4) + (l & 15);
                const int m = (d ^ (d >> 3)) & 7;
                bf16x8 vf = *(const bf16x8*)(Vt + d * 128 + ((((tg << 2) + (l >> 4)) ^ m) << 4));
                oacc[nd] = __builtin_amdgcn_mfma_f32_16x16x32_bf16(pf, vf, oacc[nd], 0, 0, 0);
            }
            lacc = __builtin_amdgcn_mfma_f32_16x16x32_bf16(pf, vones, lacc, 0, 0, 0);
        }
    }
#undef LOAD_TILE

    // epilogue: O /= l  (+ qv), bf16 store
    const size_t orow = qrow0 + ((l >> 4) << 2);
    #pragma unroll
    for (int r = 0; r < 4; ++r) {
        const float inv = 1.f / lacc[r];
        #pragma unroll
        for (int nd = 0; nd < 8; ++nd) {
            const size_t c = (l & 15) + (nd << 4);
            float v = oacc[nd][r] * inv;
            if (ADD_QV) v += bf2f(QV[bi + (orow + r) * ld + c]);
            O[bo + (orow + r) * 1024 + c] = f2bf(v);
        }
    }
}

// ---------------------------------------------------------------------------
// LayerNorm over (S,E) per batch on bf16 h1.
// ---------------------------------------------------------------------------
__global__ void ln_partial(const ushort* __restrict__ h1, float2* __restrict__ part)
{
    __shared__ float sa[8];
    const size_t off = ((size_t)blockIdx.x) << 15;
    float s = 0.f, s2 = 0.f;
    for (int i = threadIdx.x; i < 4096; i += 256) {
        uint4 u = *(const uint4*)(h1 + off + (size_t)i * 8);
        const ushort* e = (const ushort*)&u;
        #pragma unroll
        for (int j = 0; j < 8; ++j) { const float v = bf2f(e[j]); s += v; s2 += v * v; }
    }
    #pragma unroll
    for (int m = 1; m < 64; m <<= 1) { s += __shfl_xor(s, m, 64); s2 += __shfl_xor(s2, m, 64); }
    const int w = threadIdx.x >> 6;
    if ((threadIdx.x & 63) == 0) { sa[w * 2] = s; sa[w * 2 + 1] = s2; }
    __syncthreads();
    if (threadIdx.x == 0)
        part[blockIdx.x] = make_float2(sa[0] + sa[2] + sa[4] + sa[6], sa[1] + sa[3] + sa[5] + sa[7]);
}

__global__ void ln_finish(const float2* __restrict__ part, float2* __restrict__ stats)
{
    const int b = threadIdx.x;
    if (b < 8) {
        float s = 0.f, s2 = 0.f;
        for (int c = 0; c < 32; ++c) { const float2 v = part[b * 32 + c]; s += v.x; s2 += v.y; }
        const float mu = s * (1.f / 1048576.f);
        const float var = s2 * (1.f / 1048576.f) - mu * mu;
        stats[b] = make_float2(mu, rsqrtf(var + 1e-5f));
    }
}

__global__ void ln_apply(const ushort* __restrict__ h1, const float2* __restrict__ stats,
                         const float* __restrict__ gw, const float* __restrict__ gb,
                         ushort* __restrict__ hn)
{
    const size_t i = ((size_t)blockIdx.x * 256 + threadIdx.x) * 8;
    const int b = (int)(i >> 20);
    const size_t r = i & 1048575;
    const float2 st = stats[b];
    uint4 uv = *(const uint4*)(h1 + i);
    const float4 w0 = *(const float4*)(gw + r);
    const float4 w1 = *(const float4*)(gw + r + 4);
    const float4 b0 = *(const float4*)(gb + r);
    const float4 b1 = *(const float4*)(gb + r + 4);
    const float wv[8] = {w0.x, w0.y, w0.z, w0.w, w1.x, w1.y, w1.z, w1.w};
    const float bv[8] = {b0.x, b0.y, b0.z, b0.w, b1.x, b1.y, b1.z, b1.w};
    const ushort* ev = (const ushort*)&uv;
    ushort o[8];
    #pragma unroll
    for (int j = 0; j < 8; ++j)
        o[j] = f2bf((bf2f(ev[j]) - st.x) * st.y * wv[j] + bv[j]);
    *(uint4*)(hn + i) = *(const uint4*)o;
}

// ---------------------------------------------------------------------------
extern "C" void kernel_launch(void* const* d_in, const int* in_sizes, int n_in,
                              void* d_out, int out_size, void* d_ws, size_t ws_size,
                              hipStream_t stream)
{
    (void)in_sizes; (void)n_in; (void)out_size; (void)ws_size;
    auto P = [&](int i) { return (const float*)d_in[i]; };

    const size_t MB = 1u << 20;
    char* ws = (char*)d_ws;
    ushort* WB = (ushort*)ws;                       // 32 MB packed bf16 weights
    ushort* B0 = (ushort*)(ws + 32 * MB);           // 6 x 16 MB bf16 buffers
    ushort* B1 = (ushort*)(ws + 48 * MB);
    ushort* B2 = (ushort*)(ws + 64 * MB);
    ushort* B3 = (ushort*)(ws + 80 * MB);
    ushort* B4 = (ushort*)(ws + 96 * MB);
    ushort* B5 = (ushort*)(ws + 112 * MB);
    float*  BP = (float*)(ws + 128 * MB);           // 64 KB packed fp32 biases
    float2* PART = (float2*)(ws + 128 * MB + 65536);
    float2* STATS = PART + 256;

    PtrTab tab;
    const int wsrc[16] = {2,4,6,8,10,14,16,18,20,22,24,26,28,30,32,34};
    for (int i = 0; i < 16; ++i) { tab.w[i] = P(wsrc[i]); tab.b[i] = P(wsrc[i] + 1); }
    tab.x = P(0); tab.y = P(1);

    const dim3 blk(256), gg(512);
    const float SA_SCALE = 0.08838834764831845f;    // 1/sqrt(128), folded into q proj
    auto Wp = [&](int w) { return WB + (size_t)w * 1048576; };
    auto Bp = [&](int w) { return BP + (size_t)w * 1024; };
    const ushort* NUS = nullptr;

    // x_bf16 -> B4, y_bf16 -> B5
    cvt_pack<<<dim3(16392), blk, 0, stream>>>(tab, WB, B4, B5, BP);

    // --- cross attention (all GEMMs N=1024) ---
    gemm_bf16<0,0,0,ushort,ushort><<<gg, blk, 0, stream>>>(B4, Wp(0), Bp(0), NUS, B0, 1024, nullptr, 0, 1.0f);  // q  -> B0
    gemm_bf16<0,0,0,ushort,ushort><<<gg, blk, 0, stream>>>(B4, Wp(1), Bp(1), NUS, B1, 1024, nullptr, 0, 1.0f);  // qv -> B1
    gemm_bf16<0,0,0,ushort,ushort><<<gg, blk, 0, stream>>>(B5, Wp(2), Bp(2), NUS, B2, 1024, nullptr, 0, 1.0f);  // k  -> B2
    gemm_bf16<0,0,1,ushort,ushort><<<gg, blk, 0, stream>>>(B5, Wp(3), Bp(3), NUS, B3, 1024, B3, 0, 1.0f);       // kv^T -> B3
    attn_fwd<1><<<dim3(1024), blk, 0, stream>>>(B0, B2, B3, B1, B4, 1024);                                       // -> B4
    gemm_bf16<0,1,0,float,ushort><<<gg, blk, 0, stream>>>(B4, Wp(4), Bp(4), P(0), B5, 1024, nullptr, 0, 1.0f);   // h1 = x + o(ca) -> B5

    // --- LayerNorm over (S,E) per batch: h1=B5 -> hn=B0 ---
    ln_partial<<<dim3(256), blk, 0, stream>>>(B5, PART);
    ln_finish<<<dim3(1), dim3(64), 0, stream>>>(PART, STATS);
    ln_apply<<<dim3(4096), blk, 0, stream>>>(B5, STATS, P(12), P(13), B0);

    // --- FeedForward: hn=B0 -> h2=B3 ---
    gemm_bf16<1,0,0,ushort,ushort><<<gg, blk, 0, stream>>>(B0, Wp(5), Bp(5), NUS, B1, 1024, nullptr, 0, 1.0f);   // f1
    gemm_bf16<1,0,0,ushort,ushort><<<gg, blk, 0, stream>>>(B1, Wp(6), Bp(6), NUS, B2, 1024, nullptr, 0, 1.0f);   // f2
    gemm_bf16<1,1,0,ushort,ushort><<<gg, blk, 0, stream>>>(B2, Wp(7), Bp(7), B0, B3, 1024, nullptr, 0, 1.0f);    // h2 = hn + lr(f3)

    // --- self attention 1 (input h2=B3) ---
    gemm_bf16<0,0,0,ushort,ushort><<<gg, blk, 0, stream>>>(B3, Wp(8),  Bp(8),  NUS, B0, 1024, nullptr, 0, SA_SCALE); // q1*scale -> B0
    gemm_bf16<0,0,0,ushort,ushort><<<gg, blk, 0, stream>>>(B3, Wp(9),  Bp(9),  NUS, B1, 1024, nullptr, 0, 1.0f);     // k1 -> B1
    gemm_bf16<0,0,1,ushort,ushort><<<gg, blk, 0, stream>>>(B3, Wp(10), Bp(10), NUS, B2, 1024, B2, 0, 1.0f);          // v1^T -> B2
    attn_fwd<0><<<dim3(1024), blk, 0, stream>>>(B0, B1, B2, nullptr, B4, 1024);                                      // -> B4
    gemm_bf16<0,0,0,ushort,ushort><<<gg, blk, 0, stream>>>(B4, Wp(11), Bp(11), NUS, B5, 1024, nullptr, 0, 1.0f);     // h3 -> B5

    // --- self attention 2 (input h3=B5) ---
    gemm_bf16<0,0,0,ushort,ushort><<<gg, blk, 0, stream>>>(B5, Wp(12), Bp(12), NUS, B0, 1024, nullptr, 0, SA_SCALE); // q2*scale -> B0
    gemm_bf16<0,0,0,ushort,ushort><<<gg, blk, 0, stream>>>(B5, Wp(13), Bp(13), NUS, B1, 1024, nullptr, 0, 1.0f);     // k2 -> B1
    gemm_bf16<0,0,1,ushort,ushort><<<gg, blk, 0, stream>>>(B5, Wp(14), Bp(14), NUS, B2, 1024, B2, 0, 1.0f);          // v2^T -> B2
    attn_fwd<0><<<dim3(1024), blk, 0, stream>>>(B0, B1, B2, nullptr, B4, 1024);                                      // -> B4
    gemm_bf16<0,0,0,ushort,float><<<gg, blk, 0, stream>>>(B4, Wp(15), Bp(15), NUS, (float*)d_out, 1024, nullptr, 0, 1.0f);
}

// Round 17
// 759.796 us; speedup vs baseline: 1.4786x; 1.0075x over previous
//
#include <hip/hip_runtime.h>
#include <cstdint>
#include <cstddef>

#define DI __device__ __forceinline__

typedef __bf16 bf16x8 __attribute__((ext_vector_type(8)));
typedef float  f32x4  __attribute__((ext_vector_type(4)));

constexpr int kE = 1024;
constexpr int kM = 8192;
constexpr float kSlope = 0.01f;

DI float bf2f(ushort u) { union { uint32_t i; float f; } v; v.i = ((uint32_t)u) << 16; return v.f; }
DI ushort f2bf(float f) {
    union { float f; uint32_t i; } v; v.f = f;
    return (ushort)((v.i + 0x7FFFu + ((v.i >> 16) & 1u)) >> 16);
}
DI bf16x8 ld8f(const float* p) {
    const float4 f0 = *(const float4*)p;
    const float4 f1 = *(const float4*)(p + 4);
    union { bf16x8 v; ushort u[8]; } o;
    o.u[0] = f2bf(f0.x); o.u[1] = f2bf(f0.y); o.u[2] = f2bf(f0.z); o.u[3] = f2bf(f0.w);
    o.u[4] = f2bf(f1.x); o.u[5] = f2bf(f1.y); o.u[6] = f2bf(f1.z); o.u[7] = f2bf(f1.w);
    return o.v;
}
template<typename T> DI float ldf(const T* p);
template<> DI float ldf<ushort>(const ushort* p) { return bf2f(*p); }
template<> DI float ldf<float>(const float* p) { return *p; }

DI void gload16(const void* g, void* lds) {
    __builtin_amdgcn_global_load_lds((const __attribute__((address_space(1))) void*)g,
                                     (__attribute__((address_space(3))) void*)lds, 16, 0, 0);
}

// XOR swizzle helper (16B-slot granularity on bits 4..6)
DI int swz7(int r) { return ((r ^ (r >> 3)) & 7) << 4; }

// ---------------------------------------------------------------------------
// cvt_pack: fp32 weights -> packed bf16 WB; x,y -> bf16; biases -> packed fp32
// ---------------------------------------------------------------------------
struct PtrTab { const float* w[16]; const float* b[16]; const float* x; const float* y; };

__global__ __launch_bounds__(256)
void cvt_pack(PtrTab t, ushort* __restrict__ WB, ushort* __restrict__ Xb,
              ushort* __restrict__ Yb, float* __restrict__ BP)
{
    const int blk = blockIdx.x, tid = threadIdx.x;
    if (blk < 16384) {
        const float* src; ushort* dst; size_t idx;
        if (blk < 8192)       { const int w = blk >> 9; idx = (size_t)(blk & 511) * 2048 + tid * 8; src = t.w[w]; dst = WB + (size_t)w * 1048576; }
        else if (blk < 12288) { idx = (size_t)(blk - 8192) * 2048 + tid * 8;  src = t.x; dst = Xb; }
        else                  { idx = (size_t)(blk - 12288) * 2048 + tid * 8; src = t.y; dst = Yb; }
        *(bf16x8*)(dst + idx) = ld8f(src + idx);
    } else {
        const size_t i = (size_t)(blk - 16384) * 2048 + tid * 8;
        const int w = (int)(i >> 10), off = (int)(i & 1023);
        *(float4*)(BP + i)     = *(const float4*)(t.b[w] + off);
        *(float4*)(BP + i + 4) = *(const float4*)(t.b[w] + off + 4);
    }
}

// ---------------------------------------------------------------------------
// 128x128-tile bf16 GEMM: out[8192,1024] = epi((A @ W^T + bias) * oscale)
// BK=32, 4 waves(2x2), global_load_lds staging, double-buffered, slab/XCD
// swizzle. oscale pre-folds the attention 1/sqrt(d) into the q projection.
// VT mode: swapped-operand MFMA computes C^T; transposed store into
// vt_out[(b*1024 + d)*1024 + t].
// ---------------------------------------------------------------------------
template<int ACT, int RESID, int VT, typename TR, typename TO>
__global__ __launch_bounds__(256)
void gemm_bf16(const ushort* __restrict__ A, const ushort* __restrict__ W,
               const float* __restrict__ bias, const TR* __restrict__ resb,
               TO* __restrict__ out, int N, ushort* __restrict__ vt_out, int vtcol0,
               float oscale)
{
    __shared__ __align__(16) char sm[2][16384];   // [buf][A 8K | W 8K]
    constexpr int K = 1024;
    const int tid = threadIdx.x, l = tid & 63, wid = tid >> 6;
    const int wm = wid >> 1, wn = wid & 1;

    const int cpx = gridDim.x >> 3;
    const int sb = (blockIdx.x & 7) * cpx + (blockIdx.x >> 3);
    // slab decomposition: 512 blocks per slab = 64 row-tiles x 8 col-tiles
    const int slab = sb >> 9, rr = sb & 511;
    const int bm = rr >> 3, bn = (slab << 3) + (rr & 7);
    const size_t row0 = (size_t)bm << 7, col0 = (size_t)bn << 7;
    const bool isvt = VT && ((int)col0 >= vtcol0);

    // staging source precompute: o = (wid*2+i)*1024 + l*16
    const int o0 = (wid * 2) * 1024 + (l << 4), o1 = o0 + 1024;
    const int r0s = o0 >> 6, c0s = ((o0 >> 4) & 3) ^ ((r0s >> 1) & 3);
    const int r1s = o1 >> 6, c1s = ((o1 >> 4) & 3) ^ ((r1s >> 1) & 3);
    const ushort* gA0 = A + (row0 + r0s) * K + c0s * 8;
    const ushort* gA1 = A + (row0 + r1s) * K + c1s * 8;
    const ushort* gW0 = W + (col0 + r0s) * K + c0s * 8;
    const ushort* gW1 = W + (col0 + r1s) * K + c1s * 8;
    const int d0 = (wid * 2) * 1024, d1 = d0 + 1024;

    f32x4 acc[4][4] = {};

    { // prologue: stage tile 0
        gload16(gA0, sm[0] + d0); gload16(gA1, sm[0] + d1);
        gload16(gW0, sm[0] + 8192 + d0); gload16(gW1, sm[0] + 8192 + d1);
    }
    __syncthreads();

    for (int kt = 0; kt < 32; ++kt) {
        const int cur = kt & 1;
        if (kt + 1 < 32) {
            const int ko = (kt + 1) << 5;
            char* nb = sm[cur ^ 1];
            gload16(gA0 + ko, nb + d0); gload16(gA1 + ko, nb + d1);
            gload16(gW0 + ko, nb + 8192 + d0); gload16(gW1 + ko, nb + 8192 + d1);
        }
        const char* At = sm[cur];
        const char* Wt = sm[cur] + 8192;
        bf16x8 af[4], bfr[4];
        #pragma unroll
        for (int mi = 0; mi < 4; ++mi) {
            const int r = (wm << 6) + (mi << 4) + (l & 15);
            af[mi] = *(const bf16x8*)(At + r * 64 + ((((l >> 4) ^ ((r >> 1) & 3))) << 4));
        }
        #pragma unroll
        for (int ni = 0; ni < 4; ++ni) {
            const int r = (wn << 6) + (ni << 4) + (l & 15);
            bfr[ni] = *(const bf16x8*)(Wt + r * 64 + ((((l >> 4) ^ ((r >> 1) & 3))) << 4));
        }
        if (!isvt) {
            #pragma unroll
            for (int mi = 0; mi < 4; ++mi)
                #pragma unroll
                for (int ni = 0; ni < 4; ++ni)
                    acc[mi][ni] = __builtin_amdgcn_mfma_f32_16x16x32_bf16(af[mi], bfr[ni], acc[mi][ni], 0, 0, 0);
        } else {
            // swapped operands: D' = W_tile · A_tile^T = C^T
            #pragma unroll
            for (int mi = 0; mi < 4; ++mi)
                #pragma unroll
                for (int ni = 0; ni < 4; ++ni)
                    acc[mi][ni] = __builtin_amdgcn_mfma_f32_16x16x32_bf16(bfr[ni], af[mi], acc[mi][ni], 0, 0, 0);
        }
        __syncthreads();
    }

    const int cr = (l >> 4) << 2, cc = l & 15;
    if (!isvt) {
        // epilogue: C/D layout col=lane&15, row=(lane>>4)*4+reg (m89-verified)
        #pragma unroll
        for (int mi = 0; mi < 4; ++mi) {
            #pragma unroll
            for (int ni = 0; ni < 4; ++ni) {
                const size_t gr = row0 + (wm << 6) + (mi << 4) + cr;
                const size_t gc = col0 + (wn << 6) + (ni << 4) + cc;
                const float bv = bias[gc];
                #pragma unroll
                for (int r = 0; r < 4; ++r) {
                    float v = (acc[mi][ni][r] + bv) * oscale;
                    if (ACT) v = v > 0.f ? v : v * kSlope;
                    const size_t off = (gr + r) * (size_t)N + gc;
                    if (RESID) v += ldf(resb + off);
                    if constexpr (sizeof(TO) == 4) out[off] = v;
                    else                           out[off] = f2bf(v);
                }
            }
        }
    } else if (VT) {
        // D'[row=d][col=t]: d = col0-vtcol0 + (wn<<6)+(ni<<4)+cr+r, t = row0 + (wm<<6)+(mi<<4)+cc
        #pragma unroll
        for (int mi = 0; mi < 4; ++mi) {
            const size_t t_glob = row0 + (wm << 6) + (mi << 4) + cc;
            const size_t bb = t_glob >> 10;
            const int tt = (int)(t_glob & 1023);
            #pragma unroll
            for (int ni = 0; ni < 4; ++ni) {
                const int gcb = (int)col0 + (wn << 6) + (ni << 4) + cr;
                const int dbase = gcb - vtcol0;
                #pragma unroll
                for (int r = 0; r < 4; ++r) {
                    const float v = acc[mi][ni][r] + bias[gcb + r];
                    vt_out[(((bb << 10) + dbase + r) << 10) + tt] = f2bf(v);
                }
            }
        }
    }
}

// ---------------------------------------------------------------------------
// Flash attention, round 17: GEMM-style async staging.
// One block = (b, h, 64 q-rows); 4 waves x 16 q-rows. Scale pre-folded into
// the q projection. Q/K/QV bf16 row stride ld; V PRE-TRANSPOSED:
// VT[(b*8+h)*128+d][1024 t].
// K/V double-buffered in LDS, staged via global_load_lds with linear LDS
// dest + INVERSE-SWIZZLED global source (rule 21; final layout and all read
// formulas identical to the verified round-12 kernel). ONE barrier per tile:
// issue next-tile loads -> compute current -> __syncthreads (drain overlaps
// compute). Removes per tile: 1 barrier, 8 ds_write_b128, reg round trip.
//  - row-sum via ones-MFMA (lacc) = softmax denominator
//  - defer-rescale (wave-uniform __any)
//  - native __bf16 casts for P
// ---------------------------------------------------------------------------
template<int ADD_QV>
__global__ __launch_bounds__(256)
void attn_fwd(const ushort* __restrict__ Q, const ushort* __restrict__ K,
              const ushort* __restrict__ VT, const ushort* __restrict__ QV,
              ushort* __restrict__ O, int ld)
{
    __shared__ __align__(16) char KB[2][16384];    // [buf][64 rows x 256B]
    __shared__ __align__(16) char VB[2][16384];    // [buf][128 d x 128B]
    __shared__ __align__(16) char Pl[4][2048];     // per-wave 16x64 bf16

    const int tid = threadIdx.x;
    const int l = tid & 63, w = tid >> 6;

    const int cpx = gridDim.x >> 3;                 // 1024 blocks -> 128
    const int sb = (blockIdx.x & 7) * cpx + (blockIdx.x >> 3);
    const int qt = sb & 15;
    const int bh = sb >> 4;
    const int h = bh & 7, b = bh >> 3;

    const size_t bi = ((size_t)b << 10) * (size_t)ld + ((size_t)h << 7);
    const size_t bo = ((size_t)b << 10) * 1024 + ((size_t)h << 7);
    const size_t vtoff = ((size_t)bh) << 17;        // (b*8+h)*128*1024
    const size_t qrow0 = (size_t)(qt << 6) + (w << 4);

    // Q fragments (A-side: lane&15 = q-row, (lane>>4)*8 = k-offset)
    bf16x8 qf[4];
    #pragma unroll
    for (int kk = 0; kk < 4; ++kk)
        qf[kk] = *(const bf16x8*)(Q + bi + (qrow0 + (l & 15)) * ld + (kk << 5) + ((l >> 4) << 3));

    f32x4 oacc[8] = {};
    f32x4 lacc = {};                                // row-sum accumulator
    float mrow[4] = {-1e30f, -1e30f, -1e30f, -1e30f};

    bf16x8 vones;
    #pragma unroll
    for (int j = 0; j < 8; ++j) vones[j] = (__bf16)1.0f;

    // --- staging source precompute (named scalars; rule #20) ---
    // K: wave w instr i stages LDS linear [w*4096 + i*1024 + l*16]:
    //    row = w*16 + i*4 + (l>>4), slot s = l&15; source chunk = s ^ swzbits(row)
    // V: same linear dest into VB: d = w*32 + i*8 + (l>>3), slot s = l&7;
    //    source chunk = s ^ swzbits(d)   (both match round-12's final layout)
    const int kr0 = (w << 4) + 0 + (l >> 4), kr1 = kr0 + 4, kr2 = kr0 + 8, kr3 = kr0 + 12;
    const int ksl = l & 15;
    const size_t ks0 = bi + (size_t)kr0 * ld + ((ksl ^ ((kr0 ^ (kr0 >> 3)) & 7)) << 3);
    const size_t ks1 = bi + (size_t)kr1 * ld + ((ksl ^ ((kr1 ^ (kr1 >> 3)) & 7)) << 3);
    const size_t ks2 = bi + (size_t)kr2 * ld + ((ksl ^ ((kr2 ^ (kr2 >> 3)) & 7)) << 3);
    const size_t ks3 = bi + (size_t)kr3 * ld + ((ksl ^ ((kr3 ^ (kr3 >> 3)) & 7)) << 3);
    const int vd0 = (w << 5) + 0 + (l >> 3), vd1 = vd0 + 8, vd2 = vd0 + 16, vd3 = vd0 + 24;
    const int vsl = l & 7;
    const size_t vs0 = vtoff + (size_t)vd0 * 1024 + ((vsl ^ ((vd0 ^ (vd0 >> 3)) & 7)) << 3);
    const size_t vs1 = vtoff + (size_t)vd1 * 1024 + ((vsl ^ ((vd1 ^ (vd1 >> 3)) & 7)) << 3);
    const size_t vs2 = vtoff + (size_t)vd2 * 1024 + ((vsl ^ ((vd2 ^ (vd2 >> 3)) & 7)) << 3);
    const size_t vs3 = vtoff + (size_t)vd3 * 1024 + ((vsl ^ ((vd3 ^ (vd3 >> 3)) & 7)) << 3);
    const int wb = w << 12;                         // wave-uniform LDS base

#define STAGE(KT, BUF)                                                         \
    {                                                                          \
        const size_t ko = (size_t)((KT) * 64) * (size_t)ld;                    \
        char* kb = KB[BUF];                                                    \
        gload16(K + ks0 + ko, kb + wb);                                        \
        gload16(K + ks1 + ko, kb + wb + 1024);                                 \
        gload16(K + ks2 + ko, kb + wb + 2048);                                 \
        gload16(K + ks3 + ko, kb + wb + 3072);                                 \
        const size_t vo = (size_t)((KT) << 6);                                 \
        char* vb = VB[BUF];                                                    \
        gload16(VT + vs0 + vo, vb + wb);                                       \
        gload16(VT + vs1 + vo, vb + wb + 1024);                                \
        gload16(VT + vs2 + vo, vb + wb + 2048);                                \
        gload16(VT + vs3 + vo, vb + wb + 3072);                                \
    }

    STAGE(0, 0);
    __syncthreads();

    for (int kt0 = 0; kt0 < 16; ++kt0) {
        const int cur = kt0 & 1;
        if (kt0 + 1 < 16) STAGE(kt0 + 1, cur ^ 1);   // async; drains at barrier
        const char* Kt = KB[cur];
        const char* Vt = VB[cur];

        // S = Q K^T  (lane holds S[q=(l>>4)*4+r][t=(l&15)+16*ni])
        f32x4 sacc[4] = {};
        #pragma unroll
        for (int ni = 0; ni < 4; ++ni) {
            const int r = (l & 15) + (ni << 4);
            #pragma unroll
            for (int kk = 0; kk < 4; ++kk) {
                bf16x8 kf = *(const bf16x8*)(Kt + r * 256 + ((((kk << 2) + (l >> 4)) << 4) ^ swz7(r)));
                sacc[ni] = __builtin_amdgcn_mfma_f32_16x16x32_bf16(qf[kk], kf, sacc[ni], 0, 0, 0);
            }
        }

        // row max over the 16-lane t-groups
        float m0[4];
        #pragma unroll
        for (int r = 0; r < 4; ++r) {
            float m = fmaxf(fmaxf(sacc[0][r], sacc[1][r]), fmaxf(sacc[2][r], sacc[3][r]));
            #pragma unroll
            for (int msk = 1; msk < 16; msk <<= 1) m = fmaxf(m, __shfl_xor(m, msk, 64));
            m0[r] = m;
        }
        // defer-rescale: only when some row's max grew (wave-uniform branch)
        const bool grow = (m0[0] > mrow[0]) || (m0[1] > mrow[1]) ||
                          (m0[2] > mrow[2]) || (m0[3] > mrow[3]);
        if (__any(grow)) {
            float corr[4];
            #pragma unroll
            for (int r = 0; r < 4; ++r) {
                const float mn = fmaxf(mrow[r], m0[r]);
                corr[r] = __expf(mrow[r] - mn);
                mrow[r] = mn;
            }
            #pragma unroll
            for (int nd = 0; nd < 8; ++nd)
                #pragma unroll
                for (int r = 0; r < 4; ++r) oacc[nd][r] *= corr[r];
            #pragma unroll
            for (int r = 0; r < 4; ++r) lacc[r] *= corr[r];
        }

        // P = exp(S - m) -> bf16 -> per-wave LDS (A-fragment layout)
        char* pw = Pl[w];
        #pragma unroll
        for (int r = 0; r < 4; ++r) {
            const int q = ((l >> 4) << 2) + r;
            const int qo = q * 128, qm = swz7(q);
            const float mr = mrow[r];
            #pragma unroll
            for (int ni = 0; ni < 4; ++ni) {
                const float p = __expf(sacc[ni][r] - mr);
                const int t = (l & 15) + (ni << 4);
                *(__bf16*)(pw + qo + ((t * 2) ^ qm)) = (__bf16)p;
            }
        }

        // PV (+ ones-column row-sum)
        #pragma unroll
        for (int tg = 0; tg < 2; ++tg) {
            const int q = l & 15;
            bf16x8 pf = *(const bf16x8*)(pw + q * 128 + ((((tg << 2) + (l >> 4)) << 4) ^ swz7(q)));
            #pragma unroll
            for (int nd = 0; nd < 8; ++nd) {
                const int d = (nd << 4) + (l & 15);
                const int m = (d ^ (d >> 3)) & 7;
                bf16x8 vf = *(const bf16x8*)(Vt + d * 128 + ((((tg << 2) + (l >> 4)) ^ m) << 4));
                oacc[nd] = __builtin_amdgcn_mfma_f32_16x16x32_bf16(pf, vf, oacc[nd], 0, 0, 0);
            }
            lacc = __builtin_amdgcn_mfma_f32_16x16x32_bf16(pf, vones, lacc, 0, 0, 0);
        }

        __syncthreads();                      // next buf staged; this buf free
    }
#undef STAGE

    // epilogue: O /= l  (+ qv), bf16 store
    const size_t orow = qrow0 + ((l >> 4) << 2);
    #pragma unroll
    for (int r = 0; r < 4; ++r) {
        const float inv = 1.f / lacc[r];
        #pragma unroll
        for (int nd = 0; nd < 8; ++nd) {
            const size_t c = (l & 15) + (nd << 4);
            float v = oacc[nd][r] * inv;
            if (ADD_QV) v += bf2f(QV[bi + (orow + r) * ld + c]);
            O[bo + (orow + r) * 1024 + c] = f2bf(v);
        }
    }
}

// ---------------------------------------------------------------------------
// LayerNorm over (S,E) per batch on bf16 h1.
// ---------------------------------------------------------------------------
__global__ void ln_partial(const ushort* __restrict__ h1, float2* __restrict__ part)
{
    __shared__ float sa[8];
    const size_t off = ((size_t)blockIdx.x) << 15;
    float s = 0.f, s2 = 0.f;
    for (int i = threadIdx.x; i < 4096; i += 256) {
        uint4 u = *(const uint4*)(h1 + off + (size_t)i * 8);
        const ushort* e = (const ushort*)&u;
        #pragma unroll
        for (int j = 0; j < 8; ++j) { const float v = bf2f(e[j]); s += v; s2 += v * v; }
    }
    #pragma unroll
    for (int m = 1; m < 64; m <<= 1) { s += __shfl_xor(s, m, 64); s2 += __shfl_xor(s2, m, 64); }
    const int w = threadIdx.x >> 6;
    if ((threadIdx.x & 63) == 0) { sa[w * 2] = s; sa[w * 2 + 1] = s2; }
    __syncthreads();
    if (threadIdx.x == 0)
        part[blockIdx.x] = make_float2(sa[0] + sa[2] + sa[4] + sa[6], sa[1] + sa[3] + sa[5] + sa[7]);
}

__global__ void ln_finish(const float2* __restrict__ part, float2* __restrict__ stats)
{
    const int b = threadIdx.x;
    if (b < 8) {
        float s = 0.f, s2 = 0.f;
        for (int c = 0; c < 32; ++c) { const float2 v = part[b * 32 + c]; s += v.x; s2 += v.y; }
        const float mu = s * (1.f / 1048576.f);
        const float var = s2 * (1.f / 1048576.f) - mu * mu;
        stats[b] = make_float2(mu, rsqrtf(var + 1e-5f));
    }
}

__global__ void ln_apply(const ushort* __restrict__ h1, const float2* __restrict__ stats,
                         const float* __restrict__ gw, const float* __restrict__ gb,
                         ushort* __restrict__ hn)
{
    const size_t i = ((size_t)blockIdx.x * 256 + threadIdx.x) * 8;
    const int b = (int)(i >> 20);
    const size_t r = i & 1048575;
    const float2 st = stats[b];
    uint4 uv = *(const uint4*)(h1 + i);
    const float4 w0 = *(const float4*)(gw + r);
    const float4 w1 = *(const float4*)(gw + r + 4);
    const float4 b0 = *(const float4*)(gb + r);
    const float4 b1 = *(const float4*)(gb + r + 4);
    const float wv[8] = {w0.x, w0.y, w0.z, w0.w, w1.x, w1.y, w1.z, w1.w};
    const float bv[8] = {b0.x, b0.y, b0.z, b0.w, b1.x, b1.y, b1.z, b1.w};
    const ushort* ev = (const ushort*)&uv;
    ushort o[8];
    #pragma unroll
    for (int j = 0; j < 8; ++j)
        o[j] = f2bf((bf2f(ev[j]) - st.x) * st.y * wv[j] + bv[j]);
    *(uint4*)(hn + i) = *(const uint4*)o;
}

// ---------------------------------------------------------------------------
extern "C" void kernel_launch(void* const* d_in, const int* in_sizes, int n_in,
                              void* d_out, int out_size, void* d_ws, size_t ws_size,
                              hipStream_t stream)
{
    (void)in_sizes; (void)n_in; (void)out_size; (void)ws_size;
    auto P = [&](int i) { return (const float*)d_in[i]; };

    const size_t MB = 1u << 20;
    char* ws = (char*)d_ws;
    ushort* WB = (ushort*)ws;                       // 32 MB packed bf16 weights
    ushort* B0 = (ushort*)(ws + 32 * MB);           // 6 x 16 MB bf16 buffers
    ushort* B1 = (ushort*)(ws + 48 * MB);
    ushort* B2 = (ushort*)(ws + 64 * MB);
    ushort* B3 = (ushort*)(ws + 80 * MB);
    ushort* B4 = (ushort*)(ws + 96 * MB);
    ushort* B5 = (ushort*)(ws + 112 * MB);
    float*  BP = (float*)(ws + 128 * MB);           // 64 KB packed fp32 biases
    float2* PART = (float2*)(ws + 128 * MB + 65536);
    float2* STATS = PART + 256;

    PtrTab tab;
    const int wsrc[16] = {2,4,6,8,10,14,16,18,20,22,24,26,28,30,32,34};
    for (int i = 0; i < 16; ++i) { tab.w[i] = P(wsrc[i]); tab.b[i] = P(wsrc[i] + 1); }
    tab.x = P(0); tab.y = P(1);

    const dim3 blk(256), gg(512);
    const float SA_SCALE = 0.08838834764831845f;    // 1/sqrt(128), folded into q proj
    auto Wp = [&](int w) { return WB + (size_t)w * 1048576; };
    auto Bp = [&](int w) { return BP + (size_t)w * 1024; };
    const ushort* NUS = nullptr;

    // x_bf16 -> B4, y_bf16 -> B5
    cvt_pack<<<dim3(16392), blk, 0, stream>>>(tab, WB, B4, B5, BP);

    // --- cross attention (all GEMMs N=1024) ---
    gemm_bf16<0,0,0,ushort,ushort><<<gg, blk, 0, stream>>>(B4, Wp(0), Bp(0), NUS, B0, 1024, nullptr, 0, 1.0f);  // q  -> B0
    gemm_bf16<0,0,0,ushort,ushort><<<gg, blk, 0, stream>>>(B4, Wp(1), Bp(1), NUS, B1, 1024, nullptr, 0, 1.0f);  // qv -> B1
    gemm_bf16<0,0,0,ushort,ushort><<<gg, blk, 0, stream>>>(B5, Wp(2), Bp(2), NUS, B2, 1024, nullptr, 0, 1.0f);  // k  -> B2
    gemm_bf16<0,0,1,ushort,ushort><<<gg, blk, 0, stream>>>(B5, Wp(3), Bp(3), NUS, B3, 1024, B3, 0, 1.0f);       // kv^T -> B3
    attn_fwd<1><<<dim3(1024), blk, 0, stream>>>(B0, B2, B3, B1, B4, 1024);                                       // -> B4
    gemm_bf16<0,1,0,float,ushort><<<gg, blk, 0, stream>>>(B4, Wp(4), Bp(4), P(0), B5, 1024, nullptr, 0, 1.0f);   // h1 = x + o(ca) -> B5

    // --- LayerNorm over (S,E) per batch: h1=B5 -> hn=B0 ---
    ln_partial<<<dim3(256), blk, 0, stream>>>(B5, PART);
    ln_finish<<<dim3(1), dim3(64), 0, stream>>>(PART, STATS);
    ln_apply<<<dim3(4096), blk, 0, stream>>>(B5, STATS, P(12), P(13), B0);

    // --- FeedForward: hn=B0 -> h2=B3 ---
    gemm_bf16<1,0,0,ushort,ushort><<<gg, blk, 0, stream>>>(B0, Wp(5), Bp(5), NUS, B1, 1024, nullptr, 0, 1.0f);   // f1
    gemm_bf16<1,0,0,ushort,ushort><<<gg, blk, 0, stream>>>(B1, Wp(6), Bp(6), NUS, B2, 1024, nullptr, 0, 1.0f);   // f2
    gemm_bf16<1,1,0,ushort,ushort><<<gg, blk, 0, stream>>>(B2, Wp(7), Bp(7), B0, B3, 1024, nullptr, 0, 1.0f);    // h2 = hn + lr(f3)

    // --- self attention 1 (input h2=B3) ---
    gemm_bf16<0,0,0,ushort,ushort><<<gg, blk, 0, stream>>>(B3, Wp(8),  Bp(8),  NUS, B0, 1024, nullptr, 0, SA_SCALE); // q1*scale -> B0
    gemm_bf16<0,0,0,ushort,ushort><<<gg, blk, 0, stream>>>(B3, Wp(9),  Bp(9),  NUS, B1, 1024, nullptr, 0, 1.0f);     // k1 -> B1
    gemm_bf16<0,0,1,ushort,ushort><<<gg, blk, 0, stream>>>(B3, Wp(10), Bp(10), NUS, B2, 1024, B2, 0, 1.0f);          // v1^T -> B2
    attn_fwd<0><<<dim3(1024), blk, 0, stream>>>(B0, B1, B2, nullptr, B4, 1024);                                      // -> B4
    gemm_bf16<0,0,0,ushort,ushort><<<gg, blk, 0, stream>>>(B4, Wp(11), Bp(11), NUS, B5, 1024, nullptr, 0, 1.0f);     // h3 -> B5

    // --- self attention 2 (input h3=B5) ---
    gemm_bf16<0,0,0,ushort,ushort><<<gg, blk, 0, stream>>>(B5, Wp(12), Bp(12), NUS, B0, 1024, nullptr, 0, SA_SCALE); // q2*scale -> B0
    gemm_bf16<0,0,0,ushort,ushort><<<gg, blk, 0, stream>>>(B5, Wp(13), Bp(13), NUS, B1, 1024, nullptr, 0, 1.0f);     // k2 -> B1
    gemm_bf16<0,0,1,ushort,ushort><<<gg, blk, 0, stream>>>(B5, Wp(14), Bp(14), NUS, B2, 1024, B2, 0, 1.0f);          // v2^T -> B2
    attn_fwd<0><<<dim3(1024), blk, 0, stream>>>(B0, B1, B2, nullptr, B4, 1024);                                      // -> B4
    gemm_bf16<0,0,0,ushort,float><<<gg, blk, 0, stream>>>(B4, Wp(15), Bp(15), NUS, (float*)d_out, 1024, nullptr, 0, 1.0f);
}